// Round 5
// baseline (197.320 us; speedup 1.0000x reference)
//
#include <hip/hip_runtime.h>
#include <stdint.h>

typedef float v4f  __attribute__((ext_vector_type(4)));
typedef float v16f __attribute__((ext_vector_type(16)));
typedef short v8s  __attribute__((ext_vector_type(8)));
typedef uint32_t u32;

#define DEVI static __device__ __forceinline__

// fp32 -> bf16 (RNE), raw bits
DEVI unsigned short f2bf(float f) {
    u32 u = __builtin_bit_cast(u32, f);
    u = (u + 0x7fffu + ((u >> 16) & 1u)) >> 16;
    return (unsigned short)u;
}
DEVI float bf2f(unsigned short h) {
    u32 u = ((u32)h) << 16;
    return __builtin_bit_cast(float, u);
}

// async global->LDS, 16B per lane. HW dest = wave-uniform base + lane*16.
template <typename T>
DEVI void async16(const T* g, T* l) {
    __builtin_amdgcn_global_load_lds(
        (const __attribute__((address_space(1))) u32*)g,
        (__attribute__((address_space(3))) u32*)l, 16, 0, 0);
}

DEVI v4f bmfma(v8s a, v8s b, v4f c) {
    return __builtin_amdgcn_mfma_f32_16x16x32_bf16(a, b, c, 0, 0, 0);
}
DEVI v16f bmfma32(v8s a, v8s b, v16f c) {
    return __builtin_amdgcn_mfma_f32_32x32x16_bf16(a, b, c, 0, 0, 0);
}

static const size_t HSZ = 32ull * 2048 * 64;  // per q/k/v region, elements

// ---------------------------------------------------------------------------
// prep: fp32 [R][512] -> bf16, row sum-of-squares, optional row sum.
__launch_bounds__(256, 2)
__global__ void prep_rows(const float* __restrict__ X, unsigned short* __restrict__ Xb,
                          float* __restrict__ Sq, float* __restrict__ Rs, int hasRs)
{
    const int w = threadIdx.x >> 6, lane = threadIdx.x & 63;
    const int r = blockIdx.x * 4 + w;
    const float* xr = X + (size_t)r * 512 + lane * 8;
    float4 a = *(const float4*)xr;
    float4 c = *(const float4*)(xr + 4);
    float s = a.x*a.x + a.y*a.y + a.z*a.z + a.w*a.w
            + c.x*c.x + c.y*c.y + c.z*c.z + c.w*c.w;
    float sm = a.x + a.y + a.z + a.w + c.x + c.y + c.z + c.w;
    uint4 pkv;
    unsigned short* e = (unsigned short*)&pkv;
    e[0] = f2bf(a.x); e[1] = f2bf(a.y); e[2] = f2bf(a.z); e[3] = f2bf(a.w);
    e[4] = f2bf(c.x); e[5] = f2bf(c.y); e[6] = f2bf(c.z); e[7] = f2bf(c.w);
    *(uint4*)(Xb + (size_t)r * 512 + lane * 8) = pkv;
#pragma unroll
    for (int d = 32; d > 0; d >>= 1) {
        s  += __shfl_xor(s, d);
        sm += __shfl_xor(sm, d);
    }
    if (lane == 0) { Sq[r] = s; if (hasRs) Rs[r] = sm; }
}

// ---------------------------------------------------------------------------
// out_sq = sum_d (out'[r][d] + 32)^2 over bf16 out' [8192][512]; wave per row.
__launch_bounds__(256, 2)
__global__ void outsq_kernel(const unsigned short* __restrict__ Op, float* __restrict__ Osq)
{
    const int w = threadIdx.x >> 6, lane = threadIdx.x & 63;
    const int r = blockIdx.x * 4 + w;
    uint4 pk = *(const uint4*)(Op + (size_t)r * 512 + lane * 8);
    const unsigned short* e = (const unsigned short*)&pk;
    float s = 0.f;
#pragma unroll
    for (int u = 0; u < 8; ++u) { float f = bf2f(e[u]) + 32.f; s += f * f; }
#pragma unroll
    for (int d = 32; d > 0; d >>= 1) s += __shfl_xor(s, d);
    if (lane == 0) Osq[r] = s;
}

// ---------------------------------------------------------------------------
// QKV cdist GEMM. 128x128 tile, BK=64, 4 waves, 16x16x32 bf16 MFMA, XOR-8
// swizzle, global_load_lds width-16 staging. val = sqrt(max(Asq+Bsq-2dot,0))-32.
//   tt=0 (q): *2*scale*log2e -> q'' region [bh][i][d]
//   tt=1 (k): -> k' region [bh][j][d]; fused ksqc[bh][j] = sum_d k'^2 * CK
//   tt=2 (v): -> v' region TRANSPOSED [bh][d][j], via LDS-transpose epilogue
__launch_bounds__(256, 2)
__global__ void gemm_cdist(const unsigned short* __restrict__ A,
                           const unsigned short* __restrict__ B,
                           const float* __restrict__ Asq,
                           const float* __restrict__ Bsq,
                           unsigned short* __restrict__ QKV,
                           float* __restrict__ Ksqc)
{
    __shared__ unsigned short lsm[2 * 128 * 64];   // lA | lB; reused as lT in epilogue
    unsigned short* lA = lsm;
    unsigned short* lB = lsm + 128 * 64;
    const int t = threadIdx.x;
    const int lane = t & 63, w = t >> 6;
    const int low = lane & 15, quad = lane >> 4;
    const int wm = w & 1, wn = w >> 1;
    const int tM = blockIdx.x * 128, tN = blockIdx.y * 128;

    v4f acc[4][4];
#pragma unroll
    for (int a = 0; a < 4; ++a)
#pragma unroll
        for (int b = 0; b < 4; ++b) acc[a][b] = (v4f){0.f, 0.f, 0.f, 0.f};

    for (int kt = 0; kt < 512; kt += 64) {
        __syncthreads();
#pragma unroll
        for (int is = 0; is < 4; ++is) {
            int slot = is * 256 + t;
            int r = slot >> 3, bp = slot & 7;
            int bs = bp ^ (r & 7);
            async16(A + (size_t)(tM + r) * 512 + kt + bs * 8, lA + slot * 8);
            async16(B + (size_t)(tN + r) * 512 + kt + bs * 8, lB + slot * 8);
        }
        __syncthreads();

        v8s bfr[4][2];
#pragma unroll
        for (int ns = 0; ns < 4; ++ns) {
            int row = wn * 64 + ns * 16 + low;
#pragma unroll
            for (int kc = 0; kc < 2; ++kc)
                bfr[ns][kc] = *(const v8s*)(lB + (row * 8 + ((kc * 4 + quad) ^ (row & 7))) * 8);
        }
#pragma unroll
        for (int ms = 0; ms < 4; ++ms) {
            int row = wm * 64 + ms * 16 + low;
            v8s af0 = *(const v8s*)(lA + (row * 8 + ((0 + quad) ^ (row & 7))) * 8);
            v8s af1 = *(const v8s*)(lA + (row * 8 + ((4 + quad) ^ (row & 7))) * 8);
#pragma unroll
            for (int ns = 0; ns < 4; ++ns) {
                acc[ms][ns] = bmfma(af0, bfr[ns][0], acc[ms][ns]);
                acc[ms][ns] = bmfma(af1, bfr[ns][1], acc[ms][ns]);
            }
        }
    }

    const int tt = tN >> 9;  // block-uniform region id
    if (tt != 2) {
#pragma unroll
        for (int ms = 0; ms < 4; ++ms) {
#pragma unroll
            for (int reg = 0; reg < 4; ++reg) {
                const int row = tM + wm * 64 + ms * 16 + quad * 4 + reg;
                const int b = row >> 11, i = row & 2047;
                float kacc = 0.f;
#pragma unroll
                for (int ns = 0; ns < 4; ++ns) {
                    const int col = tN + wn * 64 + ns * 16 + low;
                    float dot = acc[ms][ns][reg];
                    float val = sqrtf(fmaxf(Asq[row] + Bsq[col] - 2.f * dot, 0.f)) - 32.f;
                    int h = (col >> 6) & 7, d = col & 63, bh = b * 8 + h;
                    if (tt == 0) {
                        QKV[((size_t)bh * 2048 + i) * 64 + d] =
                            f2bf(val * 0.36067376022224085f);  // 2*scale*log2e
                    } else {
                        QKV[HSZ + ((size_t)bh * 2048 + i) * 64 + d] = f2bf(val);
                        kacc += val * val;
                    }
                }
                if (tt == 1) {
#pragma unroll
                    for (int d = 1; d < 16; d <<= 1) kacc += __shfl_xor(kacc, d);
                    if (low == 0) {
                        int h = ((tN + wn * 64) >> 6) & 7;
                        Ksqc[(size_t)(b * 8 + h) * 2048 + i] = kacc * 0.18033688011112042f;
                    }
                }
            }
        }
    } else {
        // v blocks: compute all vals, then 2-pass LDS transpose for coalesced
        // [bh][d][i] stores. lT: [col 0..127][row 0..63], stride 72 shorts.
        u32 packed[4][4][2];
#pragma unroll
        for (int ms = 0; ms < 4; ++ms)
#pragma unroll
            for (int ns = 0; ns < 4; ++ns) {
                const int col = tN + wn * 64 + ns * 16 + low;
                float bs_ = Bsq[col];
#pragma unroll
                for (int rp = 0; rp < 2; ++rp) {
                    u32 pk = 0;
#pragma unroll
                    for (int sub = 0; sub < 2; ++sub) {
                        int reg = rp * 2 + sub;
                        int row = tM + wm * 64 + ms * 16 + quad * 4 + reg;
                        float val = sqrtf(fmaxf(Asq[row] + bs_
                                                - 2.f * acc[ms][ns][reg], 0.f)) - 32.f;
                        pk |= (u32)f2bf(val) << (16 * sub);
                    }
                    packed[ms][ns][rp] = pk;
                }
            }
        u32* lT32 = (u32*)lsm;
#pragma unroll
        for (int p = 0; p < 2; ++p) {
            __syncthreads();
            if (wm == p) {
#pragma unroll
                for (int ms = 0; ms < 4; ++ms)
#pragma unroll
                    for (int ns = 0; ns < 4; ++ns) {
                        int cl = wn * 64 + ns * 16 + low;
#pragma unroll
                        for (int rp = 0; rp < 2; ++rp)
                            lT32[cl * 36 + ms * 8 + quad * 2 + rp] = packed[ms][ns][rp];
                    }
            }
            __syncthreads();
#pragma unroll
            for (int cc = 0; cc < 4; ++cc) {
                int col = cc * 32 + (t >> 3);
                int i0 = (t & 7) * 8;
                uint4 vvv = *(const uint4*)(lsm + col * 72 + i0);
                int colg = tN + col;
                int h = (colg >> 6) & 7, d = colg & 63;
                int rowg = tM + p * 64 + i0;
                int b = rowg >> 11, i = rowg & 2047;
                *(uint4*)(QKV + 2 * HSZ
                          + ((size_t)((b * 8 + h) * 64 + d)) * 2048 + i) = vvv;
            }
        }
    }
}

// ---------------------------------------------------------------------------
// Flash attention v3: 32x32x16 MFMA, S^T = K.Q^T (i lands in lane&31 -> P is
// directly A-operand-shaped up to one xor-32 lane exchange). No P LDS
// round-trip. Block: 2 waves x 64 Q-rows = 128 rows; KV-split=4 (512 j each).
// Writes unnormalized partial O (bf16) + partial l (f32).
__launch_bounds__(128, 2)
__global__ void flash_attn(const unsigned short* __restrict__ Q,
                           const unsigned short* __restrict__ K,
                           const unsigned short* __restrict__ VT,
                           const float* __restrict__ Ksqc,
                           unsigned short* __restrict__ PO,
                           float* __restrict__ PL)
{
    __shared__ unsigned short lK[64 * 64];   // [j][d], XOR-8 swizzle
    __shared__ unsigned short lV[64 * 64];   // [d][j], XOR-8 swizzle
    __shared__ float lKq[64];
    const int t = threadIdx.x, lane = t & 63, w = t >> 6;
    const int i31 = lane & 31, h = lane >> 5;
    const int qt = blockIdx.x, bh = blockIdx.y, sp = blockIdx.z;
    const size_t base = (size_t)bh * (2048 * 64);
    const int row0 = qt * 128 + w * 64;
    const int j0 = sp * 512;

    // Q fragments (B-operand layout): qfr[it][kt] = Q[row0+32it+i31][16kt+8h..+7]
    v8s qfr[2][4];
#pragma unroll
    for (int it = 0; it < 2; ++it)
#pragma unroll
        for (int kt = 0; kt < 4; ++kt)
            qfr[it][kt] = *(const v8s*)(Q + base
                + (size_t)(row0 + it * 32 + i31) * 64 + kt * 16 + h * 8);

    // static per-row softmax shift: nmq = -q''_sq * 1.3862944 (per-lane scalar)
    float nmq[2];
#pragma unroll
    for (int it = 0; it < 2; ++it) {
        float s = 0.f;
#pragma unroll
        for (int kt = 0; kt < 4; ++kt) {
            const unsigned short* qe = (const unsigned short*)&qfr[it][kt];
#pragma unroll
            for (int u = 0; u < 8; ++u) { float f = bf2f(qe[u]); s += f * f; }
        }
        s += __shfl_xor(s, 32);
        nmq[it] = -s * 1.3862943611198906f;
    }

    v16f o[2][2];
    float lacc[2] = {0.f, 0.f};
#pragma unroll
    for (int it = 0; it < 2; ++it)
#pragma unroll
        for (int dt = 0; dt < 2; ++dt)
#pragma unroll
            for (int r = 0; r < 16; ++r) o[it][dt][r] = 0.f;

    const unsigned short* kg = K + base + (size_t)j0 * 64;
    const unsigned short* vg = VT + (size_t)bh * 64 * 2048 + j0;
    const float* kqg = Ksqc + (size_t)bh * 2048 + j0;

    for (int iter = 0; iter < 8; ++iter) {
        __syncthreads();
#pragma unroll
        for (int is = 0; is < 4; ++is) {
            int slot = is * 128 + t;
            int r = slot >> 3, bp = slot & 7, bs = bp ^ (r & 7);
            async16(kg + (size_t)r * 64 + bs * 8, lK + slot * 8);
        }
#pragma unroll
        for (int is = 0; is < 4; ++is) {
            int slot = is * 128 + t;
            int r = slot >> 3, bp = slot & 7, bs = bp ^ (r & 7);
            async16(vg + (size_t)r * 2048 + bs * 8, lV + slot * 8);
        }
        if (t < 16) async16(kqg + t * 4, lKq + t * 4);
        __syncthreads();
        kg += 64 * 64; vg += 64; kqg += 64;

#pragma unroll
        for (int T = 0; T < 2; ++T) {
            const int jrow = T * 32 + i31;
            v8s kf[4];
#pragma unroll
            for (int kt = 0; kt < 4; ++kt)
                kf[kt] = *(const v8s*)(lK + (jrow * 8 + ((2 * kt + h) ^ (jrow & 7))) * 8);
            v4f kqv[4];
#pragma unroll
            for (int r1 = 0; r1 < 4; ++r1)
                kqv[r1] = *(const v4f*)(lKq + T * 32 + r1 * 8 + h * 4);

            u32 pk[2][8];
#pragma unroll
            for (int it = 0; it < 2; ++it) {
                v16f sa;
#pragma unroll
                for (int r = 0; r < 16; ++r) sa[r] = nmq[it] - kqv[r >> 2][r & 3];
#pragma unroll
                for (int kt = 0; kt < 4; ++kt)
                    sa = bmfma32(kf[kt], qfr[it][kt], sa);
                float p[16];
                float ls = 0.f;
#pragma unroll
                for (int r = 0; r < 16; ++r) { p[r] = exp2f(sa[r]); ls += p[r]; }
                lacc[it] += ls;
#pragma unroll
                for (int r1 = 0; r1 < 4; ++r1) {
                    pk[it][2 * r1] = __builtin_amdgcn_perm(
                        __builtin_bit_cast(u32, p[4 * r1 + 1]),
                        __builtin_bit_cast(u32, p[4 * r1 + 0]), 0x07060302u);
                    pk[it][2 * r1 + 1] = __builtin_amdgcn_perm(
                        __builtin_bit_cast(u32, p[4 * r1 + 3]),
                        __builtin_bit_cast(u32, p[4 * r1 + 2]), 0x07060302u);
                }
            }
            // PV over the two j-16 chunks of this 32-tile
#pragma unroll
            for (int c2 = 0; c2 < 2; ++c2) {
                const int jb = 2 * (2 * T + c2);
                v8s vf[2];
#pragma unroll
                for (int dt = 0; dt < 2; ++dt) {
                    const int drow = dt * 32 + i31;
                    vf[dt] = *(const v8s*)(lV + (drow * 8 + ((jb + h) ^ (drow & 7))) * 8);
                }
#pragma unroll
                for (int it = 0; it < 2; ++it) {
                    u32 pa0 = pk[it][4 * c2 + 0], pa1 = pk[it][4 * c2 + 1];
                    u32 pb0 = pk[it][4 * c2 + 2], pb1 = pk[it][4 * c2 + 3];
                    u32 own0 = h ? pb0 : pa0, own1 = h ? pb1 : pa1;
                    u32 snd0 = h ? pa0 : pb0, snd1 = h ? pa1 : pb1;
                    u32 rcv0 = __shfl_xor(snd0, 32);
                    u32 rcv1 = __shfl_xor(snd1, 32);
                    uint4 dd;
                    dd.x = h ? rcv0 : own0; dd.y = h ? rcv1 : own1;
                    dd.z = h ? own0 : rcv0; dd.w = h ? own1 : rcv1;
                    v8s af = __builtin_bit_cast(v8s, dd);
                    o[it][0] = bmfma32(af, vf[0], o[it][0]);
                    o[it][1] = bmfma32(af, vf[1], o[it][1]);
                }
            }
        }
    }

    // epilogue: store unnormalized partials
    const int pb = (qt * 32 + bh) * 4 + sp;
    unsigned short* pob = PO + (size_t)pb * 8192;
#pragma unroll
    for (int it = 0; it < 2; ++it) lacc[it] += __shfl_xor(lacc[it], 32);
#pragma unroll
    for (int it = 0; it < 2; ++it) {
#pragma unroll
        for (int dt = 0; dt < 2; ++dt)
#pragma unroll
            for (int r = 0; r < 16; ++r) {
                int rl = w * 64 + it * 32 + (r & 3) + 8 * (r >> 2) + 4 * h;
                pob[rl * 64 + dt * 32 + i31] = f2bf(o[it][dt][r]);
            }
        if (h == 0)
            PL[(size_t)pb * 128 + w * 64 + it * 32 + i31] = lacc[it];
    }
}

// ---------------------------------------------------------------------------
// combine: outp[i][h*64+d] = sum_s po_s / sum_s l_s, bf16. Grid (32 qt64, 32 bh).
__launch_bounds__(256, 2)
__global__ void combine_kernel(const unsigned short* __restrict__ PO,
                               const float* __restrict__ PL,
                               unsigned short* __restrict__ O)
{
    const int qt = blockIdx.x, bh = blockIdx.y, t = threadIdx.x;
    const int b = bh >> 3, h = bh & 7;
    const int pbase = ((qt >> 1) * 32 + bh) * 4;
    const int rl = (qt & 1) * 64 + (t >> 2), c0 = (t & 3) * 16;
    float lsum = 0.f;
#pragma unroll
    for (int s = 0; s < 4; ++s) lsum += PL[(size_t)(pbase + s) * 128 + rl];
    float inv = 1.f / lsum;
    float accv[16];
#pragma unroll
    for (int u = 0; u < 16; ++u) accv[u] = 0.f;
    const unsigned short* a = PO + (size_t)pbase * 8192 + rl * 64 + c0;
#pragma unroll
    for (int s = 0; s < 4; ++s) {
        uint4 a0 = *(const uint4*)(a + (size_t)s * 8192);
        uint4 a1 = *(const uint4*)(a + (size_t)s * 8192 + 8);
        const unsigned short* ae = (const unsigned short*)&a0;
#pragma unroll
        for (int u = 0; u < 8; ++u) accv[u] += bf2f(ae[u]);
        ae = (const unsigned short*)&a1;
#pragma unroll
        for (int u = 0; u < 8; ++u) accv[8 + u] += bf2f(ae[u]);
    }
    uint4 o0, o1;
    unsigned short* oe = (unsigned short*)&o0;
#pragma unroll
    for (int u = 0; u < 8; ++u) oe[u] = f2bf(accv[u] * inv);
    oe = (unsigned short*)&o1;
#pragma unroll
    for (int u = 0; u < 8; ++u) oe[u] = f2bf(accv[8 + u] * inv);
    unsigned short* dst = O + ((size_t)(b * 2048 + qt * 64 + (t >> 2))) * 512 + h * 64 + c0;
    *(uint4*)dst = o0;
    *(uint4*)(dst + 8) = o1;
}

// ---------------------------------------------------------------------------
// Output cdist GEMM: 128x64 tiles -> grid (64,8)=512 blocks.
// val = sqrt(max(Asq+Bsq-2(dot+32*Brs),0)) -> fp32 OUT [8192][512].
__launch_bounds__(256, 2)
__global__ void gemm_out(const unsigned short* __restrict__ A,
                         const unsigned short* __restrict__ B,
                         const float* __restrict__ Asq,
                         const float* __restrict__ Bsq,
                         const float* __restrict__ Brs,
                         float* __restrict__ OUT)
{
    __shared__ unsigned short lA[128 * 64];
    __shared__ unsigned short lB[64 * 64];
    const int t = threadIdx.x;
    const int lane = t & 63, w = t >> 6;
    const int low = lane & 15, quad = lane >> 4;
    const int wm = w & 1, wn = w >> 1;
    const int tM = blockIdx.x * 128, tN = blockIdx.y * 64;

    v4f acc[4][2];
#pragma unroll
    for (int a = 0; a < 4; ++a)
#pragma unroll
        for (int b = 0; b < 2; ++b) acc[a][b] = (v4f){0.f, 0.f, 0.f, 0.f};

    for (int kt = 0; kt < 512; kt += 64) {
        __syncthreads();
#pragma unroll
        for (int is = 0; is < 4; ++is) {
            int slot = is * 256 + t;
            int r = slot >> 3, bp = slot & 7, bs = bp ^ (r & 7);
            async16(A + (size_t)(tM + r) * 512 + kt + bs * 8, lA + slot * 8);
        }
#pragma unroll
        for (int is = 0; is < 2; ++is) {
            int slot = is * 256 + t;
            int r = slot >> 3, bp = slot & 7, bs = bp ^ (r & 7);
            async16(B + (size_t)(tN + r) * 512 + kt + bs * 8, lB + slot * 8);
        }
        __syncthreads();

        v8s bfr[2][2];
#pragma unroll
        for (int ns = 0; ns < 2; ++ns) {
            int row = wn * 32 + ns * 16 + low;
#pragma unroll
            for (int kc = 0; kc < 2; ++kc)
                bfr[ns][kc] = *(const v8s*)(lB + (row * 8 + ((kc * 4 + quad) ^ (row & 7))) * 8);
        }
#pragma unroll
        for (int ms = 0; ms < 4; ++ms) {
            int row = wm * 64 + ms * 16 + low;
            v8s af0 = *(const v8s*)(lA + (row * 8 + ((0 + quad) ^ (row & 7))) * 8);
            v8s af1 = *(const v8s*)(lA + (row * 8 + ((4 + quad) ^ (row & 7))) * 8);
#pragma unroll
            for (int ns = 0; ns < 2; ++ns) {
                acc[ms][ns] = bmfma(af0, bfr[ns][0], acc[ms][ns]);
                acc[ms][ns] = bmfma(af1, bfr[ns][1], acc[ms][ns]);
            }
        }
    }

#pragma unroll
    for (int ms = 0; ms < 4; ++ms) {
#pragma unroll
        for (int ns = 0; ns < 2; ++ns) {
#pragma unroll
            for (int reg = 0; reg < 4; ++reg) {
                int row = tM + wm * 64 + ms * 16 + quad * 4 + reg;
                int col = tN + wn * 32 + ns * 16 + low;
                float val = sqrtf(fmaxf(Asq[row] + Bsq[col]
                                        - 2.f * (acc[ms][ns][reg] + 32.f * Brs[col]), 0.f));
                OUT[(size_t)row * 512 + col] = val;
            }
        }
    }
}

// ---------------------------------------------------------------------------
extern "C" void kernel_launch(void* const* d_in, const int* in_sizes, int n_in,
                              void* d_out, int out_size, void* d_ws, size_t ws_size,
                              hipStream_t stream)
{
    const float* x    = (const float*)d_in[0];   // [4,2048,512]
    const float* wqkv = (const float*)d_in[1];   // [1536,512]
    const float* wout = (const float*)d_in[2];   // [512,512]
    float* out = (float*)d_out;                  // [4,2048,512] fp32

    char* ws = (char*)d_ws;
    size_t off = 0;
    auto alloc = [&](size_t bytes) -> void* {
        void* p = ws + off;
        off += (bytes + 255) & ~(size_t)255;
        return p;
    };
    unsigned short* xb   = (unsigned short*)alloc(8192ull * 512 * 2);
    unsigned short* wqb  = (unsigned short*)alloc(1536ull * 512 * 2);
    unsigned short* wob  = (unsigned short*)alloc(512ull * 512 * 2);
    unsigned short* qkv  = (unsigned short*)alloc(3ull * HSZ * 2);      // q'', k', v'^T
    unsigned short* outp = (unsigned short*)alloc(8192ull * 512 * 2);
    unsigned short* po   = (unsigned short*)alloc(2048ull * 8192 * 2);  // partial O (4 splits)
    float* pl   = (float*)alloc(2048ull * 128 * 4);                     // partial l
    float* xsq  = (float*)alloc(8192 * 4);
    float* wqsq = (float*)alloc(1536 * 4);
    float* wosq = (float*)alloc(512 * 4);
    float* wors = (float*)alloc(512 * 4);
    float* ksqc = (float*)alloc(65536ull * 4);
    float* osq  = (float*)alloc(8192 * 4);

    prep_rows<<<2048, 256, 0, stream>>>(x, xb, xsq, nullptr, 0);
    prep_rows<<<384, 256, 0, stream>>>(wqkv, wqb, wqsq, nullptr, 0);
    prep_rows<<<128, 256, 0, stream>>>(wout, wob, wosq, wors, 1);

    gemm_cdist<<<dim3(64, 12), 256, 0, stream>>>(xb, wqb, xsq, wqsq, qkv, ksqc);
    flash_attn<<<dim3(16, 32, 4), 128, 0, stream>>>(qkv, qkv + HSZ, qkv + 2 * HSZ,
                                                    ksqc, po, pl);
    combine_kernel<<<dim3(32, 32), 256, 0, stream>>>(po, pl, outp);
    outsq_kernel<<<2048, 256, 0, stream>>>(outp, osq);
    gemm_out<<<dim3(64, 8), 256, 0, stream>>>(outp, wob, osq, wosq, wors, out);
}

// Round 6
// 190.429 us; speedup vs baseline: 1.0362x; 1.0362x over previous
//
#include <hip/hip_runtime.h>
#include <stdint.h>

typedef float v4f  __attribute__((ext_vector_type(4)));
typedef float v16f __attribute__((ext_vector_type(16)));
typedef short v8s  __attribute__((ext_vector_type(8)));
typedef uint32_t u32;

#define DEVI static __device__ __forceinline__

// fp32 -> bf16 (RNE), raw bits
DEVI unsigned short f2bf(float f) {
    u32 u = __builtin_bit_cast(u32, f);
    u = (u + 0x7fffu + ((u >> 16) & 1u)) >> 16;
    return (unsigned short)u;
}
DEVI float bf2f(unsigned short h) {
    u32 u = ((u32)h) << 16;
    return __builtin_bit_cast(float, u);
}

// async global->LDS, 16B per lane. HW dest = wave-uniform base + lane*16.
template <typename T>
DEVI void async16(const T* g, T* l) {
    __builtin_amdgcn_global_load_lds(
        (const __attribute__((address_space(1))) u32*)g,
        (__attribute__((address_space(3))) u32*)l, 16, 0, 0);
}

DEVI v4f bmfma(v8s a, v8s b, v4f c) {
    return __builtin_amdgcn_mfma_f32_16x16x32_bf16(a, b, c, 0, 0, 0);
}
DEVI v16f bmfma32(v8s a, v8s b, v16f c) {
    return __builtin_amdgcn_mfma_f32_32x32x16_bf16(a, b, c, 0, 0, 0);
}

static const size_t HSZ = 32ull * 2048 * 64;  // per q/k/v region, elements

// ---------------------------------------------------------------------------
// prep: fp32 [R][512] -> bf16, row sum-of-squares, optional row sum.
__launch_bounds__(256, 2)
__global__ void prep_rows(const float* __restrict__ X, unsigned short* __restrict__ Xb,
                          float* __restrict__ Sq, float* __restrict__ Rs, int hasRs)
{
    const int w = threadIdx.x >> 6, lane = threadIdx.x & 63;
    const int r = blockIdx.x * 4 + w;
    const float* xr = X + (size_t)r * 512 + lane * 8;
    float4 a = *(const float4*)xr;
    float4 c = *(const float4*)(xr + 4);
    float s = a.x*a.x + a.y*a.y + a.z*a.z + a.w*a.w
            + c.x*c.x + c.y*c.y + c.z*c.z + c.w*c.w;
    float sm = a.x + a.y + a.z + a.w + c.x + c.y + c.z + c.w;
    uint4 pkv;
    unsigned short* e = (unsigned short*)&pkv;
    e[0] = f2bf(a.x); e[1] = f2bf(a.y); e[2] = f2bf(a.z); e[3] = f2bf(a.w);
    e[4] = f2bf(c.x); e[5] = f2bf(c.y); e[6] = f2bf(c.z); e[7] = f2bf(c.w);
    *(uint4*)(Xb + (size_t)r * 512 + lane * 8) = pkv;
#pragma unroll
    for (int d = 32; d > 0; d >>= 1) {
        s  += __shfl_xor(s, d);
        sm += __shfl_xor(sm, d);
    }
    if (lane == 0) { Sq[r] = s; if (hasRs) Rs[r] = sm; }
}

// ---------------------------------------------------------------------------
// out_sq = sum_d (out'[r][d] + 32)^2 over bf16 out' [8192][512]; wave per row.
__launch_bounds__(256, 2)
__global__ void outsq_kernel(const unsigned short* __restrict__ Op, float* __restrict__ Osq)
{
    const int w = threadIdx.x >> 6, lane = threadIdx.x & 63;
    const int r = blockIdx.x * 4 + w;
    uint4 pk = *(const uint4*)(Op + (size_t)r * 512 + lane * 8);
    const unsigned short* e = (const unsigned short*)&pk;
    float s = 0.f;
#pragma unroll
    for (int u = 0; u < 8; ++u) { float f = bf2f(e[u]) + 32.f; s += f * f; }
#pragma unroll
    for (int d = 32; d > 0; d >>= 1) s += __shfl_xor(s, d);
    if (lane == 0) Osq[r] = s;
}

// ---------------------------------------------------------------------------
// QKV cdist GEMM. 128x128 tile, BK=64, 4 waves, 16x16x32 bf16 MFMA, XOR-8
// swizzle, global_load_lds width-16 staging. val = sqrt(max(Asq+Bsq-2dot,0))-32.
//   tt=0 (q): *2*scale*log2e -> q'' region [bh][i][d]
//   tt=1 (k): -> k' region [bh][j][d]; fused ksqc[bh][j] = sum_d k'^2 * CK
//   tt=2 (v): -> v' region TRANSPOSED [bh][d][j], via LDS-transpose epilogue
__launch_bounds__(256, 2)
__global__ void gemm_cdist(const unsigned short* __restrict__ A,
                           const unsigned short* __restrict__ B,
                           const float* __restrict__ Asq,
                           const float* __restrict__ Bsq,
                           unsigned short* __restrict__ QKV,
                           float* __restrict__ Ksqc)
{
    __shared__ unsigned short lsm[2 * 128 * 64];   // lA | lB; reused as lT in epilogue
    unsigned short* lA = lsm;
    unsigned short* lB = lsm + 128 * 64;
    const int t = threadIdx.x;
    const int lane = t & 63, w = t >> 6;
    const int low = lane & 15, quad = lane >> 4;
    const int wm = w & 1, wn = w >> 1;
    const int tM = blockIdx.x * 128, tN = blockIdx.y * 128;

    v4f acc[4][4];
#pragma unroll
    for (int a = 0; a < 4; ++a)
#pragma unroll
        for (int b = 0; b < 4; ++b) acc[a][b] = (v4f){0.f, 0.f, 0.f, 0.f};

    for (int kt = 0; kt < 512; kt += 64) {
        __syncthreads();
#pragma unroll
        for (int is = 0; is < 4; ++is) {
            int slot = is * 256 + t;
            int r = slot >> 3, bp = slot & 7;
            int bs = bp ^ (r & 7);
            async16(A + (size_t)(tM + r) * 512 + kt + bs * 8, lA + slot * 8);
            async16(B + (size_t)(tN + r) * 512 + kt + bs * 8, lB + slot * 8);
        }
        __syncthreads();

        v8s bfr[4][2];
#pragma unroll
        for (int ns = 0; ns < 4; ++ns) {
            int row = wn * 64 + ns * 16 + low;
#pragma unroll
            for (int kc = 0; kc < 2; ++kc)
                bfr[ns][kc] = *(const v8s*)(lB + (row * 8 + ((kc * 4 + quad) ^ (row & 7))) * 8);
        }
#pragma unroll
        for (int ms = 0; ms < 4; ++ms) {
            int row = wm * 64 + ms * 16 + low;
            v8s af0 = *(const v8s*)(lA + (row * 8 + ((0 + quad) ^ (row & 7))) * 8);
            v8s af1 = *(const v8s*)(lA + (row * 8 + ((4 + quad) ^ (row & 7))) * 8);
#pragma unroll
            for (int ns = 0; ns < 4; ++ns) {
                acc[ms][ns] = bmfma(af0, bfr[ns][0], acc[ms][ns]);
                acc[ms][ns] = bmfma(af1, bfr[ns][1], acc[ms][ns]);
            }
        }
    }

    const int tt = tN >> 9;  // block-uniform region id
    if (tt != 2) {
#pragma unroll
        for (int ms = 0; ms < 4; ++ms) {
#pragma unroll
            for (int reg = 0; reg < 4; ++reg) {
                const int row = tM + wm * 64 + ms * 16 + quad * 4 + reg;
                const int b = row >> 11, i = row & 2047;
                float kacc = 0.f;
#pragma unroll
                for (int ns = 0; ns < 4; ++ns) {
                    const int col = tN + wn * 64 + ns * 16 + low;
                    float dot = acc[ms][ns][reg];
                    float val = sqrtf(fmaxf(Asq[row] + Bsq[col] - 2.f * dot, 0.f)) - 32.f;
                    int h = (col >> 6) & 7, d = col & 63, bh = b * 8 + h;
                    if (tt == 0) {
                        QKV[((size_t)bh * 2048 + i) * 64 + d] =
                            f2bf(val * 0.36067376022224085f);  // 2*scale*log2e
                    } else {
                        QKV[HSZ + ((size_t)bh * 2048 + i) * 64 + d] = f2bf(val);
                        kacc += val * val;
                    }
                }
                if (tt == 1) {
#pragma unroll
                    for (int d = 1; d < 16; d <<= 1) kacc += __shfl_xor(kacc, d);
                    if (low == 0) {
                        int h = ((tN + wn * 64) >> 6) & 7;
                        Ksqc[(size_t)(b * 8 + h) * 2048 + i] = kacc * 0.18033688011112042f;
                    }
                }
            }
        }
    } else {
        // v blocks: compute all vals, then 2-pass LDS transpose for coalesced
        // [bh][d][i] stores. lT: [col 0..127][row 0..63], stride 72 shorts.
        u32 packed[4][4][2];
#pragma unroll
        for (int ms = 0; ms < 4; ++ms)
#pragma unroll
            for (int ns = 0; ns < 4; ++ns) {
                const int col = tN + wn * 64 + ns * 16 + low;
                float bs_ = Bsq[col];
#pragma unroll
                for (int rp = 0; rp < 2; ++rp) {
                    u32 pk = 0;
#pragma unroll
                    for (int sub = 0; sub < 2; ++sub) {
                        int reg = rp * 2 + sub;
                        int row = tM + wm * 64 + ms * 16 + quad * 4 + reg;
                        float val = sqrtf(fmaxf(Asq[row] + bs_
                                                - 2.f * acc[ms][ns][reg], 0.f)) - 32.f;
                        pk |= (u32)f2bf(val) << (16 * sub);
                    }
                    packed[ms][ns][rp] = pk;
                }
            }
        u32* lT32 = (u32*)lsm;
#pragma unroll
        for (int p = 0; p < 2; ++p) {
            __syncthreads();
            if (wm == p) {
#pragma unroll
                for (int ms = 0; ms < 4; ++ms)
#pragma unroll
                    for (int ns = 0; ns < 4; ++ns) {
                        int cl = wn * 64 + ns * 16 + low;
#pragma unroll
                        for (int rp = 0; rp < 2; ++rp)
                            lT32[cl * 36 + ms * 8 + quad * 2 + rp] = packed[ms][ns][rp];
                    }
            }
            __syncthreads();
#pragma unroll
            for (int cc = 0; cc < 4; ++cc) {
                int col = cc * 32 + (t >> 3);
                int i0 = (t & 7) * 8;
                uint4 vvv = *(const uint4*)(lsm + col * 72 + i0);
                int colg = tN + col;
                int h = (colg >> 6) & 7, d = colg & 63;
                int rowg = tM + p * 64 + i0;
                int b = rowg >> 11, i = rowg & 2047;
                *(uint4*)(QKV + 2 * HSZ
                          + ((size_t)((b * 8 + h) * 64 + d)) * 2048 + i) = vvv;
            }
        }
    }
}

// ---------------------------------------------------------------------------
// Flash attention v4: 32x32x16 MFMA, S^T = K.Q^T. 4 waves x 64 Q-rows = 256
// rows per block (K/V tile amortized over 4 waves; ~3 blocks/CU resident ->
// ~12 waves/CU). KV-split=4 (512 j per block, 8 iters).
// Writes unnormalized partial O (bf16) + partial l (f32).
__launch_bounds__(256, 2)
__global__ void flash_attn(const unsigned short* __restrict__ Q,
                           const unsigned short* __restrict__ K,
                           const unsigned short* __restrict__ VT,
                           const float* __restrict__ Ksqc,
                           unsigned short* __restrict__ PO,
                           float* __restrict__ PL)
{
    __shared__ unsigned short lK[64 * 64];   // [j][d], XOR-8 swizzle
    __shared__ unsigned short lV[64 * 64];   // [d][j], XOR-8 swizzle
    __shared__ float lKq[64];
    const int t = threadIdx.x, lane = t & 63, w = t >> 6;
    const int i31 = lane & 31, h = lane >> 5;
    const int qt = blockIdx.x, bh = blockIdx.y, sp = blockIdx.z;
    const size_t base = (size_t)bh * (2048 * 64);
    const int row0 = qt * 256 + w * 64;
    const int j0 = sp * 512;

    // Q fragments (B-operand layout): qfr[it][kt] = Q[row0+32it+i31][16kt+8h..+7]
    v8s qfr[2][4];
#pragma unroll
    for (int it = 0; it < 2; ++it)
#pragma unroll
        for (int kt = 0; kt < 4; ++kt)
            qfr[it][kt] = *(const v8s*)(Q + base
                + (size_t)(row0 + it * 32 + i31) * 64 + kt * 16 + h * 8);

    // static per-row softmax shift: nmq = -q''_sq * 1.3862944 (per-lane scalar)
    float nmq[2];
#pragma unroll
    for (int it = 0; it < 2; ++it) {
        float s = 0.f;
#pragma unroll
        for (int kt = 0; kt < 4; ++kt) {
            const unsigned short* qe = (const unsigned short*)&qfr[it][kt];
#pragma unroll
            for (int u = 0; u < 8; ++u) { float f = bf2f(qe[u]); s += f * f; }
        }
        s += __shfl_xor(s, 32);
        nmq[it] = -s * 1.3862943611198906f;
    }

    v16f o[2][2];
    float lacc[2] = {0.f, 0.f};
#pragma unroll
    for (int it = 0; it < 2; ++it)
#pragma unroll
        for (int dt = 0; dt < 2; ++dt)
#pragma unroll
            for (int r = 0; r < 16; ++r) o[it][dt][r] = 0.f;

    const unsigned short* kg = K + base + (size_t)j0 * 64;
    const unsigned short* vg = VT + (size_t)bh * 64 * 2048 + j0;
    const float* kqg = Ksqc + (size_t)bh * 2048 + j0;

    for (int iter = 0; iter < 8; ++iter) {
        __syncthreads();
#pragma unroll
        for (int is = 0; is < 2; ++is) {
            int slot = is * 256 + t;
            int r = slot >> 3, bp = slot & 7, bs = bp ^ (r & 7);
            async16(kg + (size_t)r * 64 + bs * 8, lK + slot * 8);
        }
#pragma unroll
        for (int is = 0; is < 2; ++is) {
            int slot = is * 256 + t;
            int r = slot >> 3, bp = slot & 7, bs = bp ^ (r & 7);
            async16(vg + (size_t)r * 2048 + bs * 8, lV + slot * 8);
        }
        if (t < 16) async16(kqg + t * 4, lKq + t * 4);
        __syncthreads();
        kg += 64 * 64; vg += 64; kqg += 64;

#pragma unroll
        for (int T = 0; T < 2; ++T) {
            const int jrow = T * 32 + i31;
            v8s kf[4];
#pragma unroll
            for (int kt = 0; kt < 4; ++kt)
                kf[kt] = *(const v8s*)(lK + (jrow * 8 + ((2 * kt + h) ^ (jrow & 7))) * 8);
            v4f kqv[4];
#pragma unroll
            for (int r1 = 0; r1 < 4; ++r1)
                kqv[r1] = *(const v4f*)(lKq + T * 32 + r1 * 8 + h * 4);

            u32 pk[2][8];
#pragma unroll
            for (int it = 0; it < 2; ++it) {
                v16f sa;
#pragma unroll
                for (int r = 0; r < 16; ++r) sa[r] = nmq[it] - kqv[r >> 2][r & 3];
#pragma unroll
                for (int kt = 0; kt < 4; ++kt)
                    sa = bmfma32(kf[kt], qfr[it][kt], sa);
                float p[16];
                float ls = 0.f;
#pragma unroll
                for (int r = 0; r < 16; ++r) { p[r] = exp2f(sa[r]); ls += p[r]; }
                lacc[it] += ls;
#pragma unroll
                for (int r1 = 0; r1 < 4; ++r1) {
                    pk[it][2 * r1] = __builtin_amdgcn_perm(
                        __builtin_bit_cast(u32, p[4 * r1 + 1]),
                        __builtin_bit_cast(u32, p[4 * r1 + 0]), 0x07060302u);
                    pk[it][2 * r1 + 1] = __builtin_amdgcn_perm(
                        __builtin_bit_cast(u32, p[4 * r1 + 3]),
                        __builtin_bit_cast(u32, p[4 * r1 + 2]), 0x07060302u);
                }
            }
            // PV over the two j-16 chunks of this 32-tile
#pragma unroll
            for (int c2 = 0; c2 < 2; ++c2) {
                const int jb = 2 * (2 * T + c2);
                v8s vf[2];
#pragma unroll
                for (int dt = 0; dt < 2; ++dt) {
                    const int drow = dt * 32 + i31;
                    vf[dt] = *(const v8s*)(lV + (drow * 8 + ((jb + h) ^ (drow & 7))) * 8);
                }
#pragma unroll
                for (int it = 0; it < 2; ++it) {
                    u32 pa0 = pk[it][4 * c2 + 0], pa1 = pk[it][4 * c2 + 1];
                    u32 pb0 = pk[it][4 * c2 + 2], pb1 = pk[it][4 * c2 + 3];
                    u32 own0 = h ? pb0 : pa0, own1 = h ? pb1 : pa1;
                    u32 snd0 = h ? pa0 : pb0, snd1 = h ? pa1 : pb1;
                    u32 rcv0 = __shfl_xor(snd0, 32);
                    u32 rcv1 = __shfl_xor(snd1, 32);
                    uint4 dd;
                    dd.x = h ? rcv0 : own0; dd.y = h ? rcv1 : own1;
                    dd.z = h ? own0 : rcv0; dd.w = h ? own1 : rcv1;
                    v8s af = __builtin_bit_cast(v8s, dd);
                    o[it][0] = bmfma32(af, vf[0], o[it][0]);
                    o[it][1] = bmfma32(af, vf[1], o[it][1]);
                }
            }
        }
    }

    // epilogue: store unnormalized partials. PO block: 256 rows x 64 cols.
    const int pb = (qt * 32 + bh) * 4 + sp;
    unsigned short* pob = PO + (size_t)pb * 16384;
#pragma unroll
    for (int it = 0; it < 2; ++it) lacc[it] += __shfl_xor(lacc[it], 32);
#pragma unroll
    for (int it = 0; it < 2; ++it) {
#pragma unroll
        for (int dt = 0; dt < 2; ++dt)
#pragma unroll
            for (int r = 0; r < 16; ++r) {
                int rl = w * 64 + it * 32 + (r & 3) + 8 * (r >> 2) + 4 * h;
                pob[rl * 64 + dt * 32 + i31] = f2bf(o[it][dt][r]);
            }
        if (h == 0)
            PL[(size_t)pb * 256 + w * 64 + it * 32 + i31] = lacc[it];
    }
}

// ---------------------------------------------------------------------------
// combine: outp[i][h*64+d] = sum_s po_s / sum_s l_s, bf16.
// Grid (32 i-tiles of 64, 32 bh) x 256. PO blocks are 256 rows x 64 cols x 4 sp.
__launch_bounds__(256, 2)
__global__ void combine_kernel(const unsigned short* __restrict__ PO,
                               const float* __restrict__ PL,
                               unsigned short* __restrict__ O)
{
    const int bx = blockIdx.x, bh = blockIdx.y, t = threadIdx.x;
    const int b = bh >> 3, h = bh & 7;
    const int gi = bx * 64 + (t >> 2);          // q row within bh
    const int qt = gi >> 8, rl = gi & 255;
    const int pbase = (qt * 32 + bh) * 4;
    const int c0 = (t & 3) * 16;
    float lsum = 0.f;
#pragma unroll
    for (int s = 0; s < 4; ++s) lsum += PL[(size_t)(pbase + s) * 256 + rl];
    float inv = 1.f / lsum;
    float accv[16];
#pragma unroll
    for (int u = 0; u < 16; ++u) accv[u] = 0.f;
    const unsigned short* a = PO + (size_t)pbase * 16384 + rl * 64 + c0;
#pragma unroll
    for (int s = 0; s < 4; ++s) {
        uint4 a0 = *(const uint4*)(a + (size_t)s * 16384);
        uint4 a1 = *(const uint4*)(a + (size_t)s * 16384 + 8);
        const unsigned short* ae = (const unsigned short*)&a0;
#pragma unroll
        for (int u = 0; u < 8; ++u) accv[u] += bf2f(ae[u]);
        ae = (const unsigned short*)&a1;
#pragma unroll
        for (int u = 0; u < 8; ++u) accv[8 + u] += bf2f(ae[u]);
    }
    uint4 o0, o1;
    unsigned short* oe = (unsigned short*)&o0;
#pragma unroll
    for (int u = 0; u < 8; ++u) oe[u] = f2bf(accv[u] * inv);
    oe = (unsigned short*)&o1;
#pragma unroll
    for (int u = 0; u < 8; ++u) oe[u] = f2bf(accv[8 + u] * inv);
    unsigned short* dst = O + ((size_t)(b * 2048 + gi)) * 512 + h * 64 + c0;
    *(uint4*)dst = o0;
    *(uint4*)(dst + 8) = o1;
}

// ---------------------------------------------------------------------------
// Output cdist GEMM: 128x64 tiles -> grid (64,8)=512 blocks.
// val = sqrt(max(Asq+Bsq-2(dot+32*Brs),0)) -> fp32 OUT [8192][512].
__launch_bounds__(256, 2)
__global__ void gemm_out(const unsigned short* __restrict__ A,
                         const unsigned short* __restrict__ B,
                         const float* __restrict__ Asq,
                         const float* __restrict__ Bsq,
                         const float* __restrict__ Brs,
                         float* __restrict__ OUT)
{
    __shared__ unsigned short lA[128 * 64];
    __shared__ unsigned short lB[64 * 64];
    const int t = threadIdx.x;
    const int lane = t & 63, w = t >> 6;
    const int low = lane & 15, quad = lane >> 4;
    const int wm = w & 1, wn = w >> 1;
    const int tM = blockIdx.x * 128, tN = blockIdx.y * 64;

    v4f acc[4][2];
#pragma unroll
    for (int a = 0; a < 4; ++a)
#pragma unroll
        for (int b = 0; b < 2; ++b) acc[a][b] = (v4f){0.f, 0.f, 0.f, 0.f};

    for (int kt = 0; kt < 512; kt += 64) {
        __syncthreads();
#pragma unroll
        for (int is = 0; is < 4; ++is) {
            int slot = is * 256 + t;
            int r = slot >> 3, bp = slot & 7, bs = bp ^ (r & 7);
            async16(A + (size_t)(tM + r) * 512 + kt + bs * 8, lA + slot * 8);
        }
#pragma unroll
        for (int is = 0; is < 2; ++is) {
            int slot = is * 256 + t;
            int r = slot >> 3, bp = slot & 7, bs = bp ^ (r & 7);
            async16(B + (size_t)(tN + r) * 512 + kt + bs * 8, lB + slot * 8);
        }
        __syncthreads();

        v8s bfr[2][2];
#pragma unroll
        for (int ns = 0; ns < 2; ++ns) {
            int row = wn * 32 + ns * 16 + low;
#pragma unroll
            for (int kc = 0; kc < 2; ++kc)
                bfr[ns][kc] = *(const v8s*)(lB + (row * 8 + ((kc * 4 + quad) ^ (row & 7))) * 8);
        }
#pragma unroll
        for (int ms = 0; ms < 4; ++ms) {
            int row = wm * 64 + ms * 16 + low;
            v8s af0 = *(const v8s*)(lA + (row * 8 + ((0 + quad) ^ (row & 7))) * 8);
            v8s af1 = *(const v8s*)(lA + (row * 8 + ((4 + quad) ^ (row & 7))) * 8);
#pragma unroll
            for (int ns = 0; ns < 2; ++ns) {
                acc[ms][ns] = bmfma(af0, bfr[ns][0], acc[ms][ns]);
                acc[ms][ns] = bmfma(af1, bfr[ns][1], acc[ms][ns]);
            }
        }
    }

#pragma unroll
    for (int ms = 0; ms < 4; ++ms) {
#pragma unroll
        for (int ns = 0; ns < 2; ++ns) {
#pragma unroll
            for (int reg = 0; reg < 4; ++reg) {
                int row = tM + wm * 64 + ms * 16 + quad * 4 + reg;
                int col = tN + wn * 32 + ns * 16 + low;
                float val = sqrtf(fmaxf(Asq[row] + Bsq[col]
                                        - 2.f * (acc[ms][ns][reg] + 32.f * Brs[col]), 0.f));
                OUT[(size_t)row * 512 + col] = val;
            }
        }
    }
}

// ---------------------------------------------------------------------------
extern "C" void kernel_launch(void* const* d_in, const int* in_sizes, int n_in,
                              void* d_out, int out_size, void* d_ws, size_t ws_size,
                              hipStream_t stream)
{
    const float* x    = (const float*)d_in[0];   // [4,2048,512]
    const float* wqkv = (const float*)d_in[1];   // [1536,512]
    const float* wout = (const float*)d_in[2];   // [512,512]
    float* out = (float*)d_out;                  // [4,2048,512] fp32

    char* ws = (char*)d_ws;
    size_t off = 0;
    auto alloc = [&](size_t bytes) -> void* {
        void* p = ws + off;
        off += (bytes + 255) & ~(size_t)255;
        return p;
    };
    unsigned short* xb   = (unsigned short*)alloc(8192ull * 512 * 2);
    unsigned short* wqb  = (unsigned short*)alloc(1536ull * 512 * 2);
    unsigned short* wob  = (unsigned short*)alloc(512ull * 512 * 2);
    unsigned short* qkv  = (unsigned short*)alloc(3ull * HSZ * 2);      // q'', k', v'^T
    unsigned short* outp = (unsigned short*)alloc(8192ull * 512 * 2);
    unsigned short* po   = (unsigned short*)alloc(1024ull * 16384 * 2); // partial O
    float* pl   = (float*)alloc(1024ull * 256 * 4);                     // partial l
    float* xsq  = (float*)alloc(8192 * 4);
    float* wqsq = (float*)alloc(1536 * 4);
    float* wosq = (float*)alloc(512 * 4);
    float* wors = (float*)alloc(512 * 4);
    float* ksqc = (float*)alloc(65536ull * 4);
    float* osq  = (float*)alloc(8192 * 4);

    prep_rows<<<2048, 256, 0, stream>>>(x, xb, xsq, nullptr, 0);
    prep_rows<<<384, 256, 0, stream>>>(wqkv, wqb, wqsq, nullptr, 0);
    prep_rows<<<128, 256, 0, stream>>>(wout, wob, wosq, wors, 1);

    gemm_cdist<<<dim3(64, 12), 256, 0, stream>>>(xb, wqb, xsq, wqsq, qkv, ksqc);
    flash_attn<<<dim3(8, 32, 4), 256, 0, stream>>>(qkv, qkv + HSZ, qkv + 2 * HSZ,
                                                   ksqc, po, pl);
    combine_kernel<<<dim3(32, 32), 256, 0, stream>>>(po, pl, outp);
    outsq_kernel<<<2048, 256, 0, stream>>>(outp, osq);
    gemm_out<<<dim3(64, 8), 256, 0, stream>>>(outp, wob, osq, wosq, wors, out);
}